// Round 8
// baseline (318.340 us; speedup 1.0000x reference)
//
#include <hip/hip_runtime.h>
#include <hip/hip_bf16.h>
#include <stdint.h>

#define D 1024
#define NSUP 256
#define ROWS 16384      // 4*4096
#define MB 32           // rows per block
#define LTHREADS 512    // 8 waves
#define LGRID (ROWS / MB)   // 512 blocks -> 2 blocks/CU
#define LDS_BYTES 81920     // h 64K + wbuf 16K ; 2 blocks/CU = 160K exactly

typedef __attribute__((__ext_vector_type__(8))) __bf16 bf16x8;
typedef __attribute__((__ext_vector_type__(4))) float f32x4;

#define MFMA16(a, b, c) __builtin_amdgcn_mfma_f32_16x16x32_bf16((a), (b), (c), 0, 0, 0)

__global__ void cast_k_kernel(const float* __restrict__ K, __bf16* __restrict__ Kb) {
    int i = (blockIdx.x * 256 + threadIdx.x) * 4;
    float4 v = *(const float4*)(K + i);
    __bf16 o[4] __attribute__((aligned(8)));
    o[0] = (__bf16)v.x; o[1] = (__bf16)v.y; o[2] = (__bf16)v.z; o[3] = (__bf16)v.w;
    *(uint2*)(Kb + i) = *(const uint2*)o;
}

// V [4][256][1024] f32 -> Vt [4][1024][256] bf16
__global__ void transpose_v_kernel(const float* __restrict__ V, __bf16* __restrict__ Vt) {
    __shared__ __bf16 tile[64][72];
    int l = blockIdx.z;
    int d0 = blockIdx.x * 64, n0 = blockIdx.y * 64;
    const float* Vl = V + (size_t)l * NSUP * D;
    __bf16* Vtl = Vt + (size_t)l * D * NSUP;
    for (int j = 0; j < 16; ++j) {
        int idx = j * 256 + threadIdx.x;
        int n_l = idx >> 6, d_l = idx & 63;
        tile[d_l][n_l] = (__bf16)Vl[(size_t)(n0 + n_l) * D + d0 + d_l];
    }
    __syncthreads();
    for (int j = 0; j < 16; ++j) {
        int idx = j * 256 + threadIdx.x;
        int d_l = idx >> 6, n_l = idx & 63;
        Vtl[(size_t)(d0 + d_l) * NSUP + n0 + n_l] = tile[d_l][n_l];
    }
}

// All 4 layers fused, h resident in LDS (raw bf16, XOR-swizzled rows).
// 512 thr / 8 waves / 32 rows / 2 blocks per CU. Wave wv owns score cols
// [wv*32,+32) in Phase A and d-cols [wv*128,+128) (4 chunks of 32) in Phase C.
// Normalization folded into softmax (h stored raw; rn in registers).
// No softmax max-pass: |score*rn| <= |k_row| ~ 34 -> exp2 arg <= 49, f32-safe.
// Plain __launch_bounds__(512): the one config verified to give a 128-VGPR
// budget on this toolchain (launch_bounds(512,4)/waves_per_eu produced 64 +
// massive spills in rounds 3-7).
__global__ void __launch_bounds__(LTHREADS)
fused4_kernel(const float* __restrict__ x, float* __restrict__ out,
              const __bf16* __restrict__ Kb, const __bf16* __restrict__ Vt) {
    extern __shared__ __align__(16) char pool[];
    char* wbuf = pool + 65536;
    const int tid = threadIdx.x;
    const int lane = tid & 63;
    const int wv = tid >> 6;            // wave 0..7
    const int llo = lane & 15, lhi = lane >> 4;
    const int swzk = (llo & 7) << 4;    // swizzle key for rows rf*16+llo
    const int row0 = blockIdx.x * MB;

    // ---- stage x -> raw bf16 h (swizzled) + layer-0 rn into wbuf[0:128) ----
    {
        const int srow = tid >> 4, c16 = tid & 15;
        const float* xr = x + (size_t)(row0 + srow) * D;
        const int sk = (srow & 7) << 4;
        float ss = 0.f;
        #pragma unroll
        for (int q = 0; q < 16; ++q) {
            float4 v = *(const float4*)(xr + (c16 + q * 16) * 4);
            ss += v.x * v.x + v.y * v.y + v.z * v.z + v.w * v.w;
            __bf16 t[4] __attribute__((aligned(8)));
            t[0] = (__bf16)v.x; t[1] = (__bf16)v.y; t[2] = (__bf16)v.z; t[3] = (__bf16)v.w;
            *(uint2*)(pool + srow * 2048 + (((c16 + q * 16) * 8) ^ sk)) = *(const uint2*)t;
        }
        ss += __shfl_xor(ss, 1); ss += __shfl_xor(ss, 2);
        ss += __shfl_xor(ss, 4); ss += __shfl_xor(ss, 8);
        if (c16 == 0) *(float*)(wbuf + srow * 4) = 1.f / (sqrtf(ss) + 1e-9f);
    }
    __syncthreads();

    float sqp[2][4];   // prev-layer |row|^2 wave-partials (valid for l>0)

    #pragma unroll 1
    for (int l = 0; l < 4; ++l) {
        // ---- prev layer's sq-norm partials -> wbuf[0:1K) (wbuf dead here) ----
        if (l > 0) {
            #pragma unroll
            for (int rf = 0; rf < 2; ++rf)
                #pragma unroll
                for (int r = 0; r < 4; ++r)
                    if (llo == 0)
                        *(float*)(wbuf + (rf * 16 + lhi * 4 + r) * 32 + wv * 4) = sqp[rf][r];
        }

        // ---- Phase A: scores[32x256] = h @ K^T; wave cols [wv*32,+32) ----
        f32x4 acc[2][2];
        #pragma unroll
        for (int rf = 0; rf < 2; ++rf)
            #pragma unroll
            for (int cf = 0; cf < 2; ++cf)
                acc[rf][cf] = (f32x4){0.f, 0.f, 0.f, 0.f};
        const __bf16* kb0 = Kb + (size_t)l * NSUP * D + (size_t)(wv * 32 + llo) * D + lhi * 8;
        bf16x8 kbuf[2][2];
        #pragma unroll
        for (int cf = 0; cf < 2; ++cf)
            kbuf[0][cf] = *(const bf16x8*)(kb0 + (size_t)cf * 16 * D);
        #pragma unroll
        for (int k = 0; k < 32; ++k) {
            if (k < 31) {
                #pragma unroll
                for (int cf = 0; cf < 2; ++cf)
                    kbuf[(k + 1) & 1][cf] = *(const bf16x8*)(kb0 + (size_t)cf * 16 * D + (k + 1) * 32);
            }
            bf16x8 a0 = *(const bf16x8*)(pool + llo * 2048 + ((k * 64 + lhi * 16) ^ swzk));
            bf16x8 a1 = *(const bf16x8*)(pool + (16 + llo) * 2048 + ((k * 64 + lhi * 16) ^ swzk));
            #pragma unroll
            for (int cf = 0; cf < 2; ++cf) {
                acc[0][cf] = MFMA16(a0, kbuf[k & 1][cf], acc[0][cf]);
                acc[1][cf] = MFMA16(a1, kbuf[k & 1][cf], acc[1][cf]);
            }
        }
        __syncthreads();   // bar1: A done; h dead; wbuf partials readable

        // ---- rn for this layer ----
        float rnv[2][4];
        if (l == 0) {
            #pragma unroll
            for (int rf = 0; rf < 2; ++rf)
                #pragma unroll
                for (int r = 0; r < 4; ++r)
                    rnv[rf][r] = *(const float*)(wbuf + (rf * 16 + lhi * 4 + r) * 4);
        } else {
            #pragma unroll
            for (int rf = 0; rf < 2; ++rf)
                #pragma unroll
                for (int r = 0; r < 4; ++r) {
                    const f32x4* rp = (const f32x4*)(wbuf + (rf * 16 + lhi * 4 + r) * 32);
                    f32x4 s0 = rp[0], s1 = rp[1];
                    float ss = (s0[0] + s0[1] + s0[2] + s0[3]) + (s1[0] + s1[1] + s1[2] + s1[3]);
                    rnv[rf][r] = 1.f / (sqrtf(ss) + 1e-9f);
                }
        }

        // ---- exp (no max-sub) + wave partial sums -> pool[0:1K) (h dead) ----
        float ee[2][2][4];
        #pragma unroll
        for (int rf = 0; rf < 2; ++rf)
            #pragma unroll
            for (int r = 0; r < 4; ++r) {
                float sc = rnv[rf][r] * 1.44269504f;
                float e0 = exp2f(acc[rf][0][r] * sc);
                float e1 = exp2f(acc[rf][1][r] * sc);
                ee[rf][0][r] = e0; ee[rf][1][r] = e1;
                float s = e0 + e1;
                s += __shfl_xor(s, 1); s += __shfl_xor(s, 2);
                s += __shfl_xor(s, 4); s += __shfl_xor(s, 8);
                if (llo == 0) *(float*)(pool + (rf * 16 + lhi * 4 + r) * 32 + wv * 4) = s;
            }
        __syncthreads();   // bar2: exp partials visible

        #pragma unroll
        for (int rf = 0; rf < 2; ++rf)
            #pragma unroll
            for (int r = 0; r < 4; ++r) {
                int row = rf * 16 + lhi * 4 + r;
                const f32x4* rp = (const f32x4*)(pool + row * 32);
                f32x4 s0 = rp[0], s1 = rp[1];
                float S = (s0[0] + s0[1] + s0[2] + s0[3]) + (s1[0] + s1[1] + s1[2] + s1[3]);
                float inv = 1.f / S;
                #pragma unroll
                for (int cf = 0; cf < 2; ++cf) {
                    int col = wv * 32 + cf * 16 + llo;
                    *(__bf16*)(wbuf + row * 512 + ((col * 2) ^ ((row & 7) << 4))) =
                        (__bf16)(ee[rf][cf][r] * inv);
                }
            }
        __syncthreads();   // bar3: w visible

        // ---- Phase C: out[32x1024] = w @ V; wave d-cols [wv*128,+128),
        //      4 chunks of 32 cols to keep live regs ~90 ----
        float sql[2][4];
        #pragma unroll
        for (int rf = 0; rf < 2; ++rf)
            #pragma unroll
            for (int r = 0; r < 4; ++r) sql[rf][r] = 0.f;

        #pragma unroll 1
        for (int ch = 0; ch < 4; ++ch) {
            f32x4 acc2[2][2];
            #pragma unroll
            for (int rf = 0; rf < 2; ++rf)
                #pragma unroll
                for (int c2 = 0; c2 < 2; ++c2)
                    acc2[rf][c2] = (f32x4){0.f, 0.f, 0.f, 0.f};
            const __bf16* vt0 = Vt + (size_t)l * D * NSUP
                              + (size_t)(wv * 128 + ch * 32 + llo) * NSUP + lhi * 8;
            bf16x8 vbuf[2][2];
            #pragma unroll
            for (int c2 = 0; c2 < 2; ++c2)
                vbuf[0][c2] = *(const bf16x8*)(vt0 + (size_t)c2 * 16 * NSUP);
            #pragma unroll
            for (int k = 0; k < 8; ++k) {
                if (k < 7) {
                    #pragma unroll
                    for (int c2 = 0; c2 < 2; ++c2)
                        vbuf[(k + 1) & 1][c2] = *(const bf16x8*)(vt0 + (size_t)c2 * 16 * NSUP + (k + 1) * 32);
                }
                bf16x8 a0 = *(const bf16x8*)(wbuf + llo * 512 + ((k * 64 + lhi * 16) ^ swzk));
                bf16x8 a1 = *(const bf16x8*)(wbuf + (16 + llo) * 512 + ((k * 64 + lhi * 16) ^ swzk));
                #pragma unroll
                for (int c2 = 0; c2 < 2; ++c2) {
                    acc2[0][c2] = MFMA16(a0, vbuf[k & 1][c2], acc2[0][c2]);
                    acc2[1][c2] = MFMA16(a1, vbuf[k & 1][c2], acc2[1][c2]);
                }
            }
            if (l < 3) {
                // raw-h writeback for these 32 cols + sq accumulation
                #pragma unroll
                for (int rf = 0; rf < 2; ++rf)
                    #pragma unroll
                    for (int c2 = 0; c2 < 2; ++c2)
                        #pragma unroll
                        for (int r = 0; r < 4; ++r) {
                            int row = rf * 16 + lhi * 4 + r;
                            int col = wv * 128 + ch * 32 + c2 * 16 + llo;
                            float v = acc2[rf][c2][r];
                            *(__bf16*)(pool + row * 2048 + ((col * 2) ^ ((row & 7) << 4))) = (__bf16)v;
                            sql[rf][r] += v * v;
                        }
            } else {
                // final: direct f32 stores (16-lane x 4B = 64B dense runs)
                #pragma unroll
                for (int rf = 0; rf < 2; ++rf)
                    #pragma unroll
                    for (int c2 = 0; c2 < 2; ++c2)
                        #pragma unroll
                        for (int r = 0; r < 4; ++r) {
                            int row = rf * 16 + lhi * 4 + r;
                            int col = wv * 128 + ch * 32 + c2 * 16 + llo;
                            out[(size_t)(row0 + row) * D + col] = acc2[rf][c2][r];
                        }
            }
        }

        if (l < 3) {
            #pragma unroll
            for (int rf = 0; rf < 2; ++rf)
                #pragma unroll
                for (int r = 0; r < 4; ++r) {
                    float s = sql[rf][r];
                    s += __shfl_xor(s, 1); s += __shfl_xor(s, 2);
                    s += __shfl_xor(s, 4); s += __shfl_xor(s, 8);
                    sqp[rf][r] = s;
                }
            __syncthreads();   // bar4: h ready for next layer
        }
    }
}

extern "C" void kernel_launch(void* const* d_in, const int* in_sizes, int n_in,
                              void* d_out, int out_size, void* d_ws, size_t ws_size,
                              hipStream_t stream) {
    const float* x = (const float*)d_in[0];
    const float* keys = (const float*)d_in[1];
    const float* values = (const float*)d_in[2];
    float* out = (float*)d_out;

    char* ws = (char*)d_ws;
    __bf16* Kb = (__bf16*)(ws);             // 4*256*1024*2 = 2 MB
    __bf16* Vt = (__bf16*)(ws + 2097152);   // 4*1024*256*2 = 2 MB

    (void)hipFuncSetAttribute((const void*)fused4_kernel,
                              hipFuncAttributeMaxDynamicSharedMemorySize, LDS_BYTES);

    cast_k_kernel<<<1024, 256, 0, stream>>>(keys, Kb);
    transpose_v_kernel<<<dim3(16, 4, 4), 256, 0, stream>>>(values, Vt);
    fused4_kernel<<<LGRID, LTHREADS, LDS_BYTES, stream>>>(x, out, Kb, Vt);
}